// Round 5
// baseline (453.601 us; speedup 1.0000x reference)
//
#include <hip/hip_runtime.h>
#include <math.h>

// CRF log-likelihood, B=512, S=512, T=128.
// ROUND 14: TWO BATCHES PER WAVE. R13 (247us, VALUBusy 53%) left the SIMD
// idle ~half of each step: the serial chain (barrier -> ds_read ~120cy ->
// FMA chain -> reduce -> write) is only covered by scheduler-lucky
// inter-wave overlap. Key fact: E = exp(trans) is IDENTICAL for all
// batches -> a wave interleaving two independent batch recursions pays E
// (64 floats) once and fills chain-A bubbles with chain-B issue,
// deterministically (intra-wave ILP). Block 256 thr = batches {2b,2b+1};
// grid 256 blocks = 1024 waves = 1 wave/SIMD. One lgkm barrier per step
// covers both batches. Issue per step-pair/SIMD ~560-700cyc ~= wall.
// Kept (R13 passed, absmax 0.0): lgkm-only barrier (prefetch stays in
// flight), DPP xor1/xor2 + ds_swizzle xor4 value-routed reduce with rb2
// duplication + exact 0.5f halving, xor-swizzled p buffers (0 conflicts),
// linear-domain recursion + exact accounting (Ld += log sref, double).

#define T 128
#define SLEN 512
#define BATCH 512

typedef float v2f __attribute__((ext_vector_type(2)));

static __device__ __forceinline__ float dpp_xor1(float x) {
    // quad_perm [1,0,3,2] == lane ^ 1
    return __int_as_float(__builtin_amdgcn_update_dpp(
        0, __float_as_int(x), 0xB1, 0xF, 0xF, true));
}
static __device__ __forceinline__ float dpp_xor2(float x) {
    // quad_perm [2,3,0,1] == lane ^ 2
    return __int_as_float(__builtin_amdgcn_update_dpp(
        0, __float_as_int(x), 0x4E, 0xF, 0xF, true));
}
static __device__ __forceinline__ float swz_xor4(float x) {
    // BitMode: and=0x1F, or=0, xor=4
    return __int_as_float(__builtin_amdgcn_ds_swizzle(__float_as_int(x), 0x101F));
}
static __device__ __forceinline__ void lgkm_barrier() {
    // LDS-writes-drained barrier that leaves vmcnt (global prefetch) alone.
    asm volatile("s_waitcnt lgkmcnt(0)\n\ts_barrier" ::: "memory");
}
// Bank swizzle for the 128-word p buffer: 4-word groups xor'd by (j>>5).
static __device__ __forceinline__ int pslot(int j) {
    return j ^ (((j >> 5) & 3) << 2);
}

__global__ __launch_bounds__(256, 2) void fwd_kernel(
    const float* __restrict__ em, const int* __restrict__ tags,
    const int* __restrict__ mask, const float* __restrict__ startT,
    const float* __restrict__ endT, const float* __restrict__ trans,
    float* __restrict__ ws)
{
    const int tid  = threadIdx.x;      // 0..255
    const int lane = tid & 63;
    const int w    = tid >> 6;         // wave 0..3
    const int rg   = lane & 7;         // row group: rows 16rg..16rg+15
    const int cw   = lane >> 3;        // col subgroup within wave (0..7)
    const int g    = 8 * w + cw;       // col group 0..31: cols 4g..4g+3
    const int bA   = 2 * blockIdx.x;
    const int bB   = bA + 1;
    const int rb0  = rg & 1, rb1 = (rg >> 1) & 1, rb2 = (rg >> 2) & 1;
    // After the 3 routed butterfly stages this lane owns exactly this col
    // (duplicated across the rb2 pair):
    const int mycol = 4 * g + 2 * rb0 + rb1;

    const float* embA = em + (size_t)bA * SLEN * T;
    const float* embB = em + (size_t)bB * SLEN * T;
    const int*   mkA  = mask + (size_t)bA * SLEN;
    const int*   mkB  = mask + (size_t)bB * SLEN;

    __shared__ __align__(16) float p_lds[2][2][T];   // [batch][buf][slot], 4 KB
    __shared__ float reds[2][4], redn[2][4];
    __shared__ int   redc[2][4];

    // Rotated row-chunk schedule + swizzled read slots (R12/R13: 0 conflicts).
    int rbase[4], rslot[4];
#pragma unroll
    for (int k = 0; k < 4; ++k) {
        rbase[k] = 16 * rg + 4 * ((k + rg) & 3);
        rslot[k] = pslot(rbase[k]);    // 4-word group shares one xor
    }
    const int wslot = pslot(mycol);

    // E fragment (shared by both batches): Elo[k][c] = rows (r0, r0+1),
    // Ehi = rows (r0+2, r0+3); r0 = rbase[k], col = 4g + c. 32 v2f = 64 regs.
    v2f Elo[4][4], Ehi[4][4];
    {
        const int cb = 4 * g;
#pragma unroll
        for (int k = 0; k < 4; ++k) {
            const float* t0p = trans + (rbase[k] + 0) * T + cb;
            const float* t1p = t0p + T;
            const float* t2p = t1p + T;
            const float* t3p = t2p + T;
#pragma unroll
            for (int c = 0; c < 4; ++c) {
                Elo[k][c] = (v2f){ __expf(t0p[c]), __expf(t1p[c]) };
                Ehi[k][c] = (v2f){ __expf(t2p[c]), __expf(t3p[c]) };
            }
        }
    }

    // alpha_0 in linear domain; step 1 reads buffer 1. Duplicate writers
    // store bit-identical values to the same slot: benign.
    float ppA = __expf(startT[mycol] + embA[mycol]);
    float ppB = __expf(startT[mycol] + embB[mycol]);
    p_lds[0][1][wslot] = ppA;
    p_lds[1][1][wslot] = ppB;
    double LdA = 0.0, LdB = 0.0;

    // 4-deep emission/mask prefetch per batch; exp applied off-chain.
    float emvA[4], emnA[4], emvB[4], emnB[4];
    int   mkvA[4], mknA[4], mkvB[4], mknB[4];
#pragma unroll
    for (int k = 0; k < 4; ++k) {
        emvA[k] = __expf(embA[(1 + k) * T + mycol]);
        emvB[k] = __expf(embB[(1 + k) * T + mycol]);
        mkvA[k] = mkA[1 + k];
        mkvB[k] = mkB[1 + k];
    }
    lgkm_barrier();

    for (int s0 = 1; s0 < SLEN; s0 += 4) {
#pragma unroll
        for (int k = 0; k < 4; ++k) {
            int ss = s0 + 4 + k; ss = (ss < SLEN) ? ss : (SLEN - 1);  // uniform
            emnA[k] = embA[ss * T + mycol];
            emnB[k] = embB[ss * T + mycol];
            mknA[k] = mkA[ss];
            mknB[k] = mkB[ss];
        }
#pragma unroll
        for (int k = 0; k < 4; ++k) {
            const int s = s0 + k;
            if (s < SLEN) {                       // uniform guard (511 steps)
                const int cur = (1 + k) & 1;      // == s&1, compile-time
                // Off-chain normalizers: col 0 (slot 0) of input buffers.
                const float srefA = fmaxf(p_lds[0][cur][0], 1e-30f);
                const float srefB = fmaxf(p_lds[1][cur][0], 1e-30f);
                const float ccA = __builtin_amdgcn_rcpf(srefA);
                const float ccB = __builtin_amdgcn_rcpf(srefB);
                LdA += (double)__logf(srefA);     // exact accounting
                LdB += (double)__logf(srefB);

                // p chunks (swizzled slots: conflict-free b128 reads).
                v2f pkA0[4], pkA1[4], pkB0[4], pkB1[4];
#pragma unroll
                for (int kk = 0; kk < 4; ++kk) {
                    const float4 pa = *(const float4*)&p_lds[0][cur][rslot[kk]];
                    const float4 pb = *(const float4*)&p_lds[1][cur][rslot[kk]];
                    pkA0[kk] = (v2f){ pa.x, pa.y }; pkA1[kk] = (v2f){ pa.z, pa.w };
                    pkB0[kk] = (v2f){ pb.x, pb.y }; pkB1[kk] = (v2f){ pb.z, pb.w };
                }
                // 64 pk_fma: two independent 8-deep chains per col pair.
                v2f accA[4], accB[4];
#pragma unroll
                for (int c = 0; c < 4; ++c) {
                    accA[c] = pkA0[0] * Elo[0][c];
                    accB[c] = pkB0[0] * Elo[0][c];
                }
#pragma unroll
                for (int c = 0; c < 4; ++c) {
                    accA[c] = __builtin_elementwise_fma(pkA1[0], Ehi[0][c], accA[c]);
                    accB[c] = __builtin_elementwise_fma(pkB1[0], Ehi[0][c], accB[c]);
                }
#pragma unroll
                for (int kk = 1; kk < 4; ++kk) {
#pragma unroll
                    for (int c = 0; c < 4; ++c) {
                        accA[c] = __builtin_elementwise_fma(pkA0[kk], Elo[kk][c], accA[c]);
                        accB[c] = __builtin_elementwise_fma(pkB0[kk], Elo[kk][c], accB[c]);
                        accA[c] = __builtin_elementwise_fma(pkA1[kk], Ehi[kk][c], accA[c]);
                        accB[c] = __builtin_elementwise_fma(pkB1[kk], Ehi[kk][c], accB[c]);
                    }
                }
                float svA[4], svB[4];
#pragma unroll
                for (int c = 0; c < 4; ++c) {
                    svA[c] = accA[c].x + accA[c].y;
                    svB[c] = accB[c].x + accB[c].y;
                }

                // Value-routed reduce over 8 rg lanes (3 stages), both batches.
                float v1A[2], v1B[2];
#pragma unroll
                for (int c = 0; c < 2; ++c) {
                    v1A[c] = (rb0 ? svA[c + 2] : svA[c])
                           + dpp_xor1(rb0 ? svA[c] : svA[c + 2]);
                    v1B[c] = (rb0 ? svB[c + 2] : svB[c])
                           + dpp_xor1(rb0 ? svB[c] : svB[c + 2]);
                }
                const float v2A = (rb1 ? v1A[1] : v1A[0])
                                + dpp_xor2(rb1 ? v1A[0] : v1A[1]);
                const float v2B = (rb1 ? v1B[1] : v1B[0])
                                + dpp_xor2(rb1 ? v1B[0] : v1B[1]);
                const float tA = v2A + swz_xor4(v2A);   // dup across rb2 pair
                const float tB = v2B + swz_xor4(v2B);

                // Linear-domain update; mask=0 keeps alpha (scaled by cc).
                const float pnA = tA * (emvA[k] * ccA);
                const float pnB = tB * (emvB[k] * ccB);
                ppA = (mkvA[k] > 0) ? pnA : (ppA * ccA);
                ppB = (mkvB[k] > 0) ? pnB : (ppB * ccB);
                p_lds[0][cur ^ 1][wslot] = ppA;   // dup same-value writes
                p_lds[1][cur ^ 1][wslot] = ppB;
                lgkm_barrier();                   // no vmcnt drain
            }
        }
#pragma unroll
        for (int k = 0; k < 4; ++k) {
            emvA[k] = __expf(emnA[k]); mkvA[k] = mknA[k];
            emvB[k] = __expf(emnB[k]); mkvB[k] = mknB[k];
        }
    }

    // ---- denominators: log(sum_j p_j e^endT_j) + Ld (cols duplicated 2x
    // across rb2 pairs -> exact 0.5f halving at the end) ----
    const float eendv = __expf(endT[mycol]);
    float smA = ppA * eendv, smB = ppB * eendv;
#pragma unroll
    for (int off = 32; off; off >>= 1) {
        smA += __shfl_xor(smA, off);
        smB += __shfl_xor(smB, off);
    }
    if (lane == 0) { reds[0][w] = smA; reds[1][w] = smB; }

    // ---- numerators: 2 strided steps per thread, both batches ----
    const int* tgA = tags + (size_t)bA * SLEN;
    const int* tgB = tags + (size_t)bB * SLEN;
    float nvA = 0.f, nvB = 0.f; int cntA = 0, cntB = 0;
#pragma unroll
    for (int rep = 0; rep < 2; ++rep) {
        const int s = tid + 256 * rep;
        const int mmA = mkA[s], mmB = mkB[s];
        cntA += (mmA != 0);
        cntB += (mmB != 0);
        if (s >= 1 && mmA > 0)
            nvA += trans[tgA[s - 1] * T + tgA[s]] + embA[s * T + tgA[s]];
        if (s >= 1 && mmB > 0)
            nvB += trans[tgB[s - 1] * T + tgB[s]] + embB[s * T + tgB[s]];
    }
#pragma unroll
    for (int off = 32; off; off >>= 1) {
        nvA += __shfl_xor(nvA, off); cntA += __shfl_xor(cntA, off);
        nvB += __shfl_xor(nvB, off); cntB += __shfl_xor(cntB, off);
    }
    if (lane == 0) { redn[0][w] = nvA; redc[0][w] = cntA;
                     redn[1][w] = nvB; redc[1][w] = cntB; }
    __syncthreads();
    if (tid == 0) {
        float ssA = 0.f, nsA = 0.f, ssB = 0.f, nsB = 0.f;
        int slA = 0, slB = 0;
#pragma unroll
        for (int i = 0; i < 4; ++i) {
            ssA += reds[0][i]; nsA += redn[0][i]; slA += redc[0][i];
            ssB += reds[1][i]; nsB += redn[1][i]; slB += redc[1][i];
        }
        const float denomA = __logf(0.5f * ssA) + (float)LdA;
        const float denomB = __logf(0.5f * ssB) + (float)LdB;
        const int tA0 = tgA[0], tAl = tgA[slA - 1];
        const int tB0 = tgB[0], tBl = tgB[slB - 1];
        ws[bA] = (startT[tA0] + embA[tA0] + endT[tAl] + nsA) - denomA;
        ws[bB] = (startT[tB0] + embB[tB0] + endT[tBl] + nsB) - denomB;
    }
}

__global__ __launch_bounds__(256) void reduce_kernel(
    const float* __restrict__ ws, float* __restrict__ out)
{
    const int t = threadIdx.x;          // one block of 256
    float local = 0.f;
    for (int i = t; i < BATCH; i += 256) local += ws[i];
    __shared__ float rf[256];
    rf[t] = local;
    __syncthreads();
    for (int off = 128; off > 0; off >>= 1) {
        if (t < off) rf[t] += rf[t + off];
        __syncthreads();
    }
    if (t == 0) out[0] = rf[0];
}

extern "C" void kernel_launch(void* const* d_in, const int* in_sizes, int n_in,
                              void* d_out, int out_size, void* d_ws, size_t ws_size,
                              hipStream_t stream)
{
    const float* emissions = (const float*)d_in[0];
    const int*   tags      = (const int*)d_in[1];
    const int*   mask      = (const int*)d_in[2];
    const float* startT    = (const float*)d_in[3];
    const float* endT      = (const float*)d_in[4];
    const float* trans     = (const float*)d_in[5];
    float* out = (float*)d_out;
    float* ws  = (float*)d_ws;          // BATCH floats of per-batch partials

    fwd_kernel<<<BATCH / 2, 256, 0, stream>>>(emissions, tags, mask, startT, endT, trans, ws);
    reduce_kernel<<<1, 256, 0, stream>>>(ws, out);
}

// Round 6
// 392.208 us; speedup vs baseline: 1.1565x; 1.1565x over previous
//
#include <hip/hip_runtime.h>
#include <math.h>

// CRF log-likelihood, B=512, S=512, T=128.
// ROUND 15: 8 WAVES/BATCH -> 4 WAVES/SIMD. R14 post-mortem: 1 wave/SIMD
// cannot hide the barrier wait (both its chains stall at the SAME barrier);
// R13 showed independent-wave TLP is the lever. So shrink the per-wave
// slice further: 512 thr/block, lane owns 1 col x 32 rows -> E = 32 floats
// (16 v2f, no AGPR pressure), per-wave issue ~60 insts/step. 512 blocks x
// 8 waves = 4096 waves = 4/SIMD (from 2 different batches): issue ~480cyc
// covers the ~250cyc chain; barrier wait of one batch filled by the other.
// Reduce is now a 2-stage plain DPP butterfly (4 lanes/col) - no ds_swizzle
// stage, shortest chain yet; result duplicated x4, exact 0.25f fix at end.
// Bank layout (pslot swizzle, no rotation needed): read instr k has rg
// groups at bank-quads {4k,4k^4,4k^8,4k^12} - disjoint; 16 cg lanes/rg
// share one address -> broadcast (free). rg==0 writes: 16 distinct banks.
// Kept (R13/R14 passed, absmax 0.0): lgkm-only barrier (prefetch stays in
// flight), xor-swizzled p double-buffer, linear-domain recursion + exact
// accounting (Ld += log sref, double).

#define T 128
#define SLEN 512
#define BATCH 512

typedef float v2f __attribute__((ext_vector_type(2)));

static __device__ __forceinline__ float dpp_xor1(float x) {
    // quad_perm [1,0,3,2] == lane ^ 1
    return __int_as_float(__builtin_amdgcn_update_dpp(
        0, __float_as_int(x), 0xB1, 0xF, 0xF, true));
}
static __device__ __forceinline__ float dpp_xor2(float x) {
    // quad_perm [2,3,0,1] == lane ^ 2
    return __int_as_float(__builtin_amdgcn_update_dpp(
        0, __float_as_int(x), 0x4E, 0xF, 0xF, true));
}
static __device__ __forceinline__ void lgkm_barrier() {
    // LDS-writes-drained barrier that leaves vmcnt (global prefetch) alone.
    asm volatile("s_waitcnt lgkmcnt(0)\n\ts_barrier" ::: "memory");
}
// Bank swizzle for the 128-word p buffer: 4-word groups xor'd by (j>>5).
static __device__ __forceinline__ int pslot(int j) {
    return j ^ (((j >> 5) & 3) << 2);
}

__global__ __launch_bounds__(512, 4) void fwd_kernel(
    const float* __restrict__ em, const int* __restrict__ tags,
    const int* __restrict__ mask, const float* __restrict__ startT,
    const float* __restrict__ endT, const float* __restrict__ trans,
    float* __restrict__ ws)
{
    const int tid  = threadIdx.x;      // 0..511
    const int lane = tid & 63;
    const int w    = tid >> 6;         // wave 0..7
    const int rg   = lane & 3;         // row group: rows 32rg..32rg+31
    const int cg   = lane >> 2;        // col within wave: 0..15
    const int b    = blockIdx.x;
    const int mycol = 16 * w + cg;     // this lane's column (dup x4 over rg)

    const float* emb = em + (size_t)b * SLEN * T;
    const int*   mk  = mask + (size_t)b * SLEN;

    __shared__ __align__(16) float p_lds[2][T];   // double buffer, 1 KB
    __shared__ float reds[8], redn[8];
    __shared__ int   redc[8];

    // Read slots: instr k reads rows 32rg+4k..+3 at swizzled slot
    // (32rg+4k)^(rg<<2)  [(j>>5)&3 == rg for this j range].
    int rslot[8];
#pragma unroll
    for (int k = 0; k < 8; ++k)
        rslot[k] = (32 * rg + 4 * k) ^ (rg << 2);
    const int wslot = pslot(mycol);

    // E fragment: Elo[k] = (exp(trans[j][col]), exp(trans[j+1][col])),
    // Ehi[k] = rows (j+2, j+3); j = 32rg + 4k.  16 v2f = 32 regs.
    v2f Elo[8], Ehi[8];
#pragma unroll
    for (int k = 0; k < 8; ++k) {
        const float* tp = trans + (32 * rg + 4 * k) * T + mycol;
        Elo[k] = (v2f){ __expf(tp[0 * T]), __expf(tp[1 * T]) };
        Ehi[k] = (v2f){ __expf(tp[2 * T]), __expf(tp[3 * T]) };
    }

    // alpha_0 in linear domain; step 1 reads buffer 1. Only rg==0 writes
    // (16 distinct banks per wave).
    float pprev = __expf(startT[mycol] + emb[mycol]);
    if (rg == 0) p_lds[1][wslot] = pprev;
    double Ld = 0.0;

    // 4-deep emission/mask prefetch; exp applied off-chain.
    float emv[4], emn[4];
    int   mkv[4], mkn[4];
#pragma unroll
    for (int k = 0; k < 4; ++k) {
        emv[k] = __expf(emb[(1 + k) * T + mycol]);
        mkv[k] = mk[1 + k];
    }
    lgkm_barrier();

    for (int s0 = 1; s0 < SLEN; s0 += 4) {
#pragma unroll
        for (int k = 0; k < 4; ++k) {
            int ss = s0 + 4 + k; ss = (ss < SLEN) ? ss : (SLEN - 1);  // uniform
            emn[k] = emb[ss * T + mycol];
            mkn[k] = mk[ss];
        }
#pragma unroll
        for (int k = 0; k < 4; ++k) {
            const int s = s0 + k;
            if (s < SLEN) {                       // uniform guard (511 steps)
                const int cur = (1 + k) & 1;      // == s&1, compile-time
                // Off-chain normalizer: col 0 (slot 0), broadcast read.
                const float srefc = fmaxf(p_lds[cur][0], 1e-30f);
                const float cc = __builtin_amdgcn_rcpf(srefc);
                Ld += (double)__logf(srefc);      // exact accounting

                // 8 b128 reads: rg groups at disjoint bank quads; 16 cg
                // lanes per rg share the address (broadcast, free).
                v2f pk0[8], pk1[8];
#pragma unroll
                for (int k2 = 0; k2 < 8; ++k2) {
                    const float4 pv = *(const float4*)&p_lds[cur][rslot[k2]];
                    pk0[k2] = (v2f){ pv.x, pv.y };
                    pk1[k2] = (v2f){ pv.z, pv.w };
                }
                // 16 pk_fma in two 8-deep chains.
                v2f accE = pk0[0] * Elo[0];
                v2f accO = pk1[0] * Ehi[0];
#pragma unroll
                for (int k2 = 1; k2 < 8; ++k2) {
                    accE = __builtin_elementwise_fma(pk0[k2], Elo[k2], accE);
                    accO = __builtin_elementwise_fma(pk1[k2], Ehi[k2], accO);
                }
                const v2f accT = accE + accO;
                const float sv = accT.x + accT.y;

                // 2-stage plain DPP butterfly over the 4 rg lanes.
                float t = sv + dpp_xor1(sv);
                t = t + dpp_xor2(t);              // all 4 lanes: full column sum

                // Linear-domain update; mask=0 keeps alpha (scaled by cc).
                const float pn = t * (emv[k] * cc);
                const float pm = pprev * cc;
                pprev = (mkv[k] > 0) ? pn : pm;
                if (rg == 0) p_lds[cur ^ 1][wslot] = pprev;
                lgkm_barrier();                   // no vmcnt drain
            }
        }
#pragma unroll
        for (int k = 0; k < 4; ++k) { emv[k] = __expf(emn[k]); mkv[k] = mkn[k]; }
    }

    // ---- denominator: log(sum_j p_j e^endT_j) + Ld  (cols duplicated x4
    // over rg -> exact 0.25f fix) ----
    const float eendv = __expf(endT[mycol]);
    float sm = pprev * eendv;
#pragma unroll
    for (int off = 32; off; off >>= 1) sm += __shfl_xor(sm, off);
    if (lane == 0) reds[w] = sm;

    // ---- numerator: 1 step per thread ----
    const int* tg = tags + (size_t)b * SLEN;
    float nv = 0.f; int cnt = 0;
    {
        const int s = tid;
        const int mm = mk[s];
        cnt += (mm != 0);
        if (s >= 1 && mm > 0)
            nv += trans[tg[s - 1] * T + tg[s]] + emb[s * T + tg[s]];
    }
#pragma unroll
    for (int off = 32; off; off >>= 1) {
        nv  += __shfl_xor(nv, off);
        cnt += __shfl_xor(cnt, off);
    }
    if (lane == 0) { redn[w] = nv; redc[w] = cnt; }
    __syncthreads();
    if (tid == 0) {
        float ssum = 0.f, nsum = 0.f; int seqlen = 0;
#pragma unroll
        for (int i = 0; i < 8; ++i) {
            ssum += reds[i]; nsum += redn[i]; seqlen += redc[i];
        }
        const float denom = __logf(0.25f * ssum) + (float)Ld;  // exact /4
        const int t0g = tg[0], tl = tg[seqlen - 1];
        ws[b] = (startT[t0g] + emb[t0g] + endT[tl] + nsum) - denom;
    }
}

__global__ __launch_bounds__(256) void reduce_kernel(
    const float* __restrict__ ws, float* __restrict__ out)
{
    const int t = threadIdx.x;          // one block of 256
    float local = 0.f;
    for (int i = t; i < BATCH; i += 256) local += ws[i];
    __shared__ float rf[256];
    rf[t] = local;
    __syncthreads();
    for (int off = 128; off > 0; off >>= 1) {
        if (t < off) rf[t] += rf[t + off];
        __syncthreads();
    }
    if (t == 0) out[0] = rf[0];
}

extern "C" void kernel_launch(void* const* d_in, const int* in_sizes, int n_in,
                              void* d_out, int out_size, void* d_ws, size_t ws_size,
                              hipStream_t stream)
{
    const float* emissions = (const float*)d_in[0];
    const int*   tags      = (const int*)d_in[1];
    const int*   mask      = (const int*)d_in[2];
    const float* startT    = (const float*)d_in[3];
    const float* endT      = (const float*)d_in[4];
    const float* trans     = (const float*)d_in[5];
    float* out = (float*)d_out;
    float* ws  = (float*)d_ws;          // BATCH floats of per-batch partials

    fwd_kernel<<<BATCH, 512, 0, stream>>>(emissions, tags, mask, startT, endT, trans, ws);
    reduce_kernel<<<1, 256, 0, stream>>>(ws, out);
}

// Round 7
// 336.275 us; speedup vs baseline: 1.3489x; 1.1663x over previous
//
#include <hip/hip_runtime.h>
#include <math.h>

// CRF log-likelihood, B=512, S=512, T=128.
// ROUND 16: R13 shape (4 waves/batch, 2 indep blocks/CU - best so far,
// 247us) + three per-step cost cuts:
//  1. Lane re-partition rg=lane&3 (32 rows), cg=lane>>2 (2 cols/lane):
//     reduce = 2 plain DPP quad_perm stages (xor1, xor2) - the ds_swizzle
//     xor4 DS-op (~40-60 chain cyc, R13) is GONE. FMA = 32 pk_fma in 4
//     independent depth-8 chains. 8 b128 reads; bank-quads k2^rg disjoint
//     per instr; 16 cg lanes broadcast (free). Writers rg<2: 32 distinct
//     banks.
//  2. Normalize every 4th step only (k==0): between normalizations growth
//     <= (128*1.1*e^4.5)^4 * e^9 ~ 1e20 << 3.4e38, no underflow. Saves
//     sref-read/log/rcp/fmax/double-add + muls on 3 of 4 steps; Ld has
//     128 log terms instead of 511 (less rounding, still exact scaled-
//     linear accounting in double).
//  3. E stays 64 floats/lane (R13-proven footprint).
// Kept: lgkm-only barrier (emission prefetch stays in flight), xor-
// swizzled p double-buffer (slot = j ^ (((j>>5)&3)<<2), 0 conflicts
// measured R12-R15), linear-domain recursion, 4-deep prefetch, rb-dup
// reduce with exact 0.5f fix.

#define T 128
#define SLEN 512
#define BATCH 512

typedef float v2f __attribute__((ext_vector_type(2)));

static __device__ __forceinline__ float dpp_xor1(float x) {
    // quad_perm [1,0,3,2] == lane ^ 1
    return __int_as_float(__builtin_amdgcn_update_dpp(
        0, __float_as_int(x), 0xB1, 0xF, 0xF, true));
}
static __device__ __forceinline__ float dpp_xor2(float x) {
    // quad_perm [2,3,0,1] == lane ^ 2
    return __int_as_float(__builtin_amdgcn_update_dpp(
        0, __float_as_int(x), 0x4E, 0xF, 0xF, true));
}
static __device__ __forceinline__ void lgkm_barrier() {
    // LDS-writes-drained barrier that leaves vmcnt (global prefetch) alone.
    asm volatile("s_waitcnt lgkmcnt(0)\n\ts_barrier" ::: "memory");
}
// Bank swizzle for the 128-word p buffer: 4-word groups xor'd by (j>>5).
static __device__ __forceinline__ int pslot(int j) {
    return j ^ (((j >> 5) & 3) << 2);
}

__global__ __launch_bounds__(256, 2) void fwd_kernel(
    const float* __restrict__ em, const int* __restrict__ tags,
    const int* __restrict__ mask, const float* __restrict__ startT,
    const float* __restrict__ endT, const float* __restrict__ trans,
    float* __restrict__ ws)
{
    const int tid  = threadIdx.x;      // 0..255
    const int lane = tid & 63;
    const int w    = tid >> 6;         // wave 0..3: cols 32w..32w+31
    const int rg   = lane & 3;         // row group: rows 32rg..32rg+31
    const int cg   = lane >> 2;        // col pair within wave: 0..15
    const int b    = blockIdx.x;
    const int rb0  = rg & 1;
    const int colbase = 32 * w + 2 * cg;       // lane's col pair {cb, cb+1}
    const int mycol   = colbase + rb0;         // final owned col (dup x2)

    const float* emb = em + (size_t)b * SLEN * T;
    const int*   mk  = mask + (size_t)b * SLEN;

    __shared__ __align__(16) float p_lds[2][T];   // double buffer, 1 KB
    __shared__ float reds[4], redn[4];
    __shared__ int   redc[4];

    // Read slots: instr k2 reads rows 32rg+4k2..+3 at swizzled slot
    // 32rg + 4*(k2^rg)  [(j>>5)&3 == rg in this range].
    int rslot[8];
#pragma unroll
    for (int k2 = 0; k2 < 8; ++k2)
        rslot[k2] = 32 * rg + 4 * (k2 ^ rg);
    const int wslot = pslot(mycol);

    // E fragment: for col c in {0,1} of the pair, rows r = 32rg+4k2:
    // Elo[c][k2] = (e^trans[r][cb+c], e^trans[r+1][cb+c]); Ehi = r+2, r+3.
    // 32 v2f = 64 regs (same footprint as R13).
    v2f Elo[2][8], Ehi[2][8];
#pragma unroll
    for (int k2 = 0; k2 < 8; ++k2) {
        const float* tp = trans + (32 * rg + 4 * k2) * T + colbase;
#pragma unroll
        for (int c = 0; c < 2; ++c) {
            Elo[c][k2] = (v2f){ __expf(tp[0 * T + c]), __expf(tp[1 * T + c]) };
            Ehi[c][k2] = (v2f){ __expf(tp[2 * T + c]), __expf(tp[3 * T + c]) };
        }
    }

    // alpha_0 in linear domain; step 1 reads buffer 1. Writers rg<2 only
    // (32 distinct banks per wave); all lanes keep pprev (dup x2 over rg>>1).
    float pprev = __expf(startT[mycol] + emb[mycol]);
    if (rg < 2) p_lds[1][wslot] = pprev;
    double Ld = 0.0;

    // 4-deep emission/mask prefetch; exp applied off-chain.
    float emv[4], emn[4];
    int   mkv[4], mkn[4];
#pragma unroll
    for (int k = 0; k < 4; ++k) {
        emv[k] = __expf(emb[(1 + k) * T + mycol]);
        mkv[k] = mk[1 + k];
    }
    lgkm_barrier();

    for (int s0 = 1; s0 < SLEN; s0 += 4) {
#pragma unroll
        for (int k = 0; k < 4; ++k) {
            int ss = s0 + 4 + k; ss = (ss < SLEN) ? ss : (SLEN - 1);  // uniform
            emn[k] = emb[ss * T + mycol];
            mkn[k] = mk[ss];
        }
#pragma unroll
        for (int k = 0; k < 4; ++k) {
            const int s = s0 + k;
            if (s < SLEN) {                       // uniform guard (511 steps)
                const int cur = (1 + k) & 1;      // == s&1, compile-time
                // Normalize only on k==0 (s = 1 mod 4): 128 of 511 steps.
                float cc = 1.0f;
                if (k == 0) {
                    const float srefc = fmaxf(p_lds[cur][0], 1e-30f);
                    cc = __builtin_amdgcn_rcpf(srefc);
                    Ld += (double)__logf(srefc);  // exact accounting
                }

                // 8 b128 reads (bank-quads k2^rg: conflict-free; cg bcast).
                v2f pk0[8], pk1[8];
#pragma unroll
                for (int k2 = 0; k2 < 8; ++k2) {
                    const float4 pv = *(const float4*)&p_lds[cur][rslot[k2]];
                    pk0[k2] = (v2f){ pv.x, pv.y };
                    pk1[k2] = (v2f){ pv.z, pv.w };
                }
                // 32 pk_fma in 4 independent depth-8 chains (2 cols x E/O).
                v2f a0e = pk0[0] * Elo[0][0];
                v2f a0o = pk1[0] * Ehi[0][0];
                v2f a1e = pk0[0] * Elo[1][0];
                v2f a1o = pk1[0] * Ehi[1][0];
#pragma unroll
                for (int k2 = 1; k2 < 8; ++k2) {
                    a0e = __builtin_elementwise_fma(pk0[k2], Elo[0][k2], a0e);
                    a0o = __builtin_elementwise_fma(pk1[k2], Ehi[0][k2], a0o);
                    a1e = __builtin_elementwise_fma(pk0[k2], Elo[1][k2], a1e);
                    a1o = __builtin_elementwise_fma(pk1[k2], Ehi[1][k2], a1o);
                }
                const v2f s0v = a0e + a0o, s1v = a1e + a1o;
                const float sv0 = s0v.x + s0v.y;
                const float sv1 = s1v.x + s1v.y;

                // 2-stage DPP value-routed reduce over 4 rg lanes.
                // After xor1: lane holds col (cb+rb0), rows 0-63 (rg<2) or
                // 64-127 (rg>=2). After xor2: full column sum, dup x2.
                const float v1 = (rb0 ? sv1 : sv0)
                               + dpp_xor1(rb0 ? sv0 : sv1);
                const float t  = v1 + dpp_xor2(v1);

                // Linear-domain update; mask=0 keeps alpha (scaled on
                // normalize steps only).
                float pn, pm;
                if (k == 0) { pn = t * (emv[k] * cc); pm = pprev * cc; }
                else        { pn = t * emv[k];        pm = pprev;      }
                pprev = (mkv[k] > 0) ? pn : pm;
                if (rg < 2) p_lds[cur ^ 1][wslot] = pprev;
                lgkm_barrier();                   // no vmcnt drain
            }
        }
#pragma unroll
        for (int k = 0; k < 4; ++k) { emv[k] = __expf(emn[k]); mkv[k] = mkn[k]; }
    }

    // ---- denominator: log(sum_j p_j e^endT_j) + Ld  (cols dup x2 over
    // rg>>1 -> exact 0.5f fix) ----
    const float eendv = __expf(endT[mycol]);
    float sm = pprev * eendv;
#pragma unroll
    for (int off = 32; off; off >>= 1) sm += __shfl_xor(sm, off);
    if (lane == 0) reds[w] = sm;

    // ---- numerator: 2 strided steps per thread ----
    const int* tg = tags + (size_t)b * SLEN;
    float nv = 0.f; int cnt = 0;
#pragma unroll
    for (int rep = 0; rep < 2; ++rep) {
        const int s = tid + 256 * rep;
        const int mm = mk[s];
        cnt += (mm != 0);
        if (s >= 1 && mm > 0)
            nv += trans[tg[s - 1] * T + tg[s]] + emb[s * T + tg[s]];
    }
#pragma unroll
    for (int off = 32; off; off >>= 1) {
        nv  += __shfl_xor(nv, off);
        cnt += __shfl_xor(cnt, off);
    }
    if (lane == 0) { redn[w] = nv; redc[w] = cnt; }
    __syncthreads();
    if (tid == 0) {
        float ssum = 0.f, nsum = 0.f; int seqlen = 0;
#pragma unroll
        for (int i = 0; i < 4; ++i) {
            ssum += reds[i]; nsum += redn[i]; seqlen += redc[i];
        }
        const float denom = __logf(0.5f * ssum) + (float)Ld;  // exact /2
        const int t0g = tg[0], tl = tg[seqlen - 1];
        ws[b] = (startT[t0g] + emb[t0g] + endT[tl] + nsum) - denom;
    }
}

__global__ __launch_bounds__(256) void reduce_kernel(
    const float* __restrict__ ws, float* __restrict__ out)
{
    const int t = threadIdx.x;          // one block of 256
    float local = 0.f;
    for (int i = t; i < BATCH; i += 256) local += ws[i];
    __shared__ float rf[256];
    rf[t] = local;
    __syncthreads();
    for (int off = 128; off > 0; off >>= 1) {
        if (t < off) rf[t] += rf[t + off];
        __syncthreads();
    }
    if (t == 0) out[0] = rf[0];
}

extern "C" void kernel_launch(void* const* d_in, const int* in_sizes, int n_in,
                              void* d_out, int out_size, void* d_ws, size_t ws_size,
                              hipStream_t stream)
{
    const float* emissions = (const float*)d_in[0];
    const int*   tags      = (const int*)d_in[1];
    const int*   mask      = (const int*)d_in[2];
    const float* startT    = (const float*)d_in[3];
    const float* endT      = (const float*)d_in[4];
    const float* trans     = (const float*)d_in[5];
    float* out = (float*)d_out;
    float* ws  = (float*)d_ws;          // BATCH floats of per-batch partials

    fwd_kernel<<<BATCH, 256, 0, stream>>>(emissions, tags, mask, startT, endT, trans, ws);
    reduce_kernel<<<1, 256, 0, stream>>>(ws, out);
}

// Round 8
// 335.974 us; speedup vs baseline: 1.3501x; 1.0009x over previous
//
#include <hip/hip_runtime.h>
#include <math.h>

// CRF log-likelihood, B=512, S=512, T=128.
// ROUND 17: R16 (205us, best) + two scheduling fixes, structure unchanged.
// R16 wall decomposition: 963 cyc/step vs chain ~350 and issue ~220/wave.
// Residual = post-barrier interference (prefetch loads issue before the
// chain-feeding ds_reads) + no arbitration between the 2 co-resident
// waves (independent blocks at different phases).
//  1. Group prefetch (4 em + 4 mk loads) moved INTO step k==0, after its
//     ds_write and right before its barrier - the wave is about to stall
//     there anyway, so those issue slots are free; the post-barrier burst
//     is now pure ds_read -> FMA.
//  2. s_setprio(1) around the chain section (normalizer..reduce), (0)
//     during write/prefetch/barrier. 2 waves/SIMD from INDEPENDENT blocks
//     = the m191-positive regime (different phases -> priority lets the
//     data-ready wave preempt the other's bookkeeping).
// Everything else identical to R16 (passed, absmax 0.0): 4 waves/batch,
// rg=lane&3 (32 rows), 2 cols/lane, 2-stage DPP reduce, normalize every
// 4th step, lgkm-only barrier, xor-swizzled p double-buffer, linear-domain
// recursion + exact double Ld accounting.

#define T 128
#define SLEN 512
#define BATCH 512

typedef float v2f __attribute__((ext_vector_type(2)));

static __device__ __forceinline__ float dpp_xor1(float x) {
    // quad_perm [1,0,3,2] == lane ^ 1
    return __int_as_float(__builtin_amdgcn_update_dpp(
        0, __float_as_int(x), 0xB1, 0xF, 0xF, true));
}
static __device__ __forceinline__ float dpp_xor2(float x) {
    // quad_perm [2,3,0,1] == lane ^ 2
    return __int_as_float(__builtin_amdgcn_update_dpp(
        0, __float_as_int(x), 0x4E, 0xF, 0xF, true));
}
static __device__ __forceinline__ void lgkm_barrier() {
    // LDS-writes-drained barrier that leaves vmcnt (global prefetch) alone.
    asm volatile("s_waitcnt lgkmcnt(0)\n\ts_barrier" ::: "memory");
}
// Bank swizzle for the 128-word p buffer: 4-word groups xor'd by (j>>5).
static __device__ __forceinline__ int pslot(int j) {
    return j ^ (((j >> 5) & 3) << 2);
}

__global__ __launch_bounds__(256, 2) void fwd_kernel(
    const float* __restrict__ em, const int* __restrict__ tags,
    const int* __restrict__ mask, const float* __restrict__ startT,
    const float* __restrict__ endT, const float* __restrict__ trans,
    float* __restrict__ ws)
{
    const int tid  = threadIdx.x;      // 0..255
    const int lane = tid & 63;
    const int w    = tid >> 6;         // wave 0..3: cols 32w..32w+31
    const int rg   = lane & 3;         // row group: rows 32rg..32rg+31
    const int cg   = lane >> 2;        // col pair within wave: 0..15
    const int b    = blockIdx.x;
    const int rb0  = rg & 1;
    const int colbase = 32 * w + 2 * cg;       // lane's col pair {cb, cb+1}
    const int mycol   = colbase + rb0;         // final owned col (dup x2)

    const float* emb = em + (size_t)b * SLEN * T;
    const int*   mk  = mask + (size_t)b * SLEN;

    __shared__ __align__(16) float p_lds[2][T];   // double buffer, 1 KB
    __shared__ float reds[4], redn[4];
    __shared__ int   redc[4];

    // Read slots: instr k2 reads rows 32rg+4k2..+3 at swizzled slot
    // 32rg + 4*(k2^rg)  [(j>>5)&3 == rg in this range].
    int rslot[8];
#pragma unroll
    for (int k2 = 0; k2 < 8; ++k2)
        rslot[k2] = 32 * rg + 4 * (k2 ^ rg);
    const int wslot = pslot(mycol);

    // E fragment: for col c in {0,1} of the pair, rows r = 32rg+4k2:
    // Elo[c][k2] = (e^trans[r][cb+c], e^trans[r+1][cb+c]); Ehi = r+2, r+3.
    // 32 v2f = 64 regs.
    v2f Elo[2][8], Ehi[2][8];
#pragma unroll
    for (int k2 = 0; k2 < 8; ++k2) {
        const float* tp = trans + (32 * rg + 4 * k2) * T + colbase;
#pragma unroll
        for (int c = 0; c < 2; ++c) {
            Elo[c][k2] = (v2f){ __expf(tp[0 * T + c]), __expf(tp[1 * T + c]) };
            Ehi[c][k2] = (v2f){ __expf(tp[2 * T + c]), __expf(tp[3 * T + c]) };
        }
    }

    // alpha_0 in linear domain; step 1 reads buffer 1. Writers rg<2 only
    // (32 distinct banks per wave); all lanes keep pprev (dup x2 over rg>>1).
    float pprev = __expf(startT[mycol] + emb[mycol]);
    if (rg < 2) p_lds[1][wslot] = pprev;
    double Ld = 0.0;

    // 4-deep emission/mask prefetch; exp applied off-chain.
    float emv[4], emn[4];
    int   mkv[4], mkn[4];
#pragma unroll
    for (int k = 0; k < 4; ++k) {
        emv[k] = __expf(emb[(1 + k) * T + mycol]);
        mkv[k] = mk[1 + k];
    }
    lgkm_barrier();

    for (int s0 = 1; s0 < SLEN; s0 += 4) {
#pragma unroll
        for (int k = 0; k < 4; ++k) {
            const int s = s0 + k;
            if (s < SLEN) {                       // uniform guard (511 steps)
                const int cur = (1 + k) & 1;      // == s&1, compile-time
                __builtin_amdgcn_s_setprio(1);    // chain section: prioritize
                // Normalize only on k==0 (s = 1 mod 4): 128 of 511 steps.
                float cc = 1.0f;
                if (k == 0) {
                    const float srefc = fmaxf(p_lds[cur][0], 1e-30f);
                    cc = __builtin_amdgcn_rcpf(srefc);
                    Ld += (double)__logf(srefc);  // exact accounting
                }

                // 8 b128 reads (bank-quads k2^rg: conflict-free; cg bcast).
                v2f pk0[8], pk1[8];
#pragma unroll
                for (int k2 = 0; k2 < 8; ++k2) {
                    const float4 pv = *(const float4*)&p_lds[cur][rslot[k2]];
                    pk0[k2] = (v2f){ pv.x, pv.y };
                    pk1[k2] = (v2f){ pv.z, pv.w };
                }
                // 32 pk_fma in 4 independent depth-8 chains (2 cols x E/O).
                v2f a0e = pk0[0] * Elo[0][0];
                v2f a0o = pk1[0] * Ehi[0][0];
                v2f a1e = pk0[0] * Elo[1][0];
                v2f a1o = pk1[0] * Ehi[1][0];
#pragma unroll
                for (int k2 = 1; k2 < 8; ++k2) {
                    a0e = __builtin_elementwise_fma(pk0[k2], Elo[0][k2], a0e);
                    a0o = __builtin_elementwise_fma(pk1[k2], Ehi[0][k2], a0o);
                    a1e = __builtin_elementwise_fma(pk0[k2], Elo[1][k2], a1e);
                    a1o = __builtin_elementwise_fma(pk1[k2], Ehi[1][k2], a1o);
                }
                const v2f s0v = a0e + a0o, s1v = a1e + a1o;
                const float sv0 = s0v.x + s0v.y;
                const float sv1 = s1v.x + s1v.y;

                // 2-stage DPP value-routed reduce over 4 rg lanes.
                const float v1 = (rb0 ? sv1 : sv0)
                               + dpp_xor1(rb0 ? sv0 : sv1);
                const float t  = v1 + dpp_xor2(v1);

                // Linear-domain update; mask=0 keeps alpha (scaled on
                // normalize steps only).
                float pn, pm;
                if (k == 0) { pn = t * (emv[k] * cc); pm = pprev * cc; }
                else        { pn = t * emv[k];        pm = pprev;      }
                pprev = (mkv[k] > 0) ? pn : pm;
                if (rg < 2) p_lds[cur ^ 1][wslot] = pprev;
                __builtin_amdgcn_s_setprio(0);    // end chain section

                // Group prefetch issued while this wave heads into its
                // barrier stall (free issue slots; vmcnt not drained by
                // the lgkm barrier).
                if (k == 0) {
#pragma unroll
                    for (int kk = 0; kk < 4; ++kk) {
                        int ss = s0 + 4 + kk;
                        ss = (ss < SLEN) ? ss : (SLEN - 1);   // uniform
                        emn[kk] = emb[ss * T + mycol];
                        mkn[kk] = mk[ss];
                    }
                }
                lgkm_barrier();                   // no vmcnt drain
            }
        }
#pragma unroll
        for (int k = 0; k < 4; ++k) { emv[k] = __expf(emn[k]); mkv[k] = mkn[k]; }
    }

    // ---- denominator: log(sum_j p_j e^endT_j) + Ld  (cols dup x2 over
    // rg>>1 -> exact 0.5f fix) ----
    const float eendv = __expf(endT[mycol]);
    float sm = pprev * eendv;
#pragma unroll
    for (int off = 32; off; off >>= 1) sm += __shfl_xor(sm, off);
    if (lane == 0) reds[w] = sm;

    // ---- numerator: 2 strided steps per thread ----
    const int* tg = tags + (size_t)b * SLEN;
    float nv = 0.f; int cnt = 0;
#pragma unroll
    for (int rep = 0; rep < 2; ++rep) {
        const int s = tid + 256 * rep;
        const int mm = mk[s];
        cnt += (mm != 0);
        if (s >= 1 && mm > 0)
            nv += trans[tg[s - 1] * T + tg[s]] + emb[s * T + tg[s]];
    }
#pragma unroll
    for (int off = 32; off; off >>= 1) {
        nv  += __shfl_xor(nv, off);
        cnt += __shfl_xor(cnt, off);
    }
    if (lane == 0) { redn[w] = nv; redc[w] = cnt; }
    __syncthreads();
    if (tid == 0) {
        float ssum = 0.f, nsum = 0.f; int seqlen = 0;
#pragma unroll
        for (int i = 0; i < 4; ++i) {
            ssum += reds[i]; nsum += redn[i]; seqlen += redc[i];
        }
        const float denom = __logf(0.5f * ssum) + (float)Ld;  // exact /2
        const int t0g = tg[0], tl = tg[seqlen - 1];
        ws[b] = (startT[t0g] + emb[t0g] + endT[tl] + nsum) - denom;
    }
}

__global__ __launch_bounds__(256) void reduce_kernel(
    const float* __restrict__ ws, float* __restrict__ out)
{
    const int t = threadIdx.x;          // one block of 256
    float local = 0.f;
    for (int i = t; i < BATCH; i += 256) local += ws[i];
    __shared__ float rf[256];
    rf[t] = local;
    __syncthreads();
    for (int off = 128; off > 0; off >>= 1) {
        if (t < off) rf[t] += rf[t + off];
        __syncthreads();
    }
    if (t == 0) out[0] = rf[0];
}

extern "C" void kernel_launch(void* const* d_in, const int* in_sizes, int n_in,
                              void* d_out, int out_size, void* d_ws, size_t ws_size,
                              hipStream_t stream)
{
    const float* emissions = (const float*)d_in[0];
    const int*   tags      = (const int*)d_in[1];
    const int*   mask      = (const int*)d_in[2];
    const float* startT    = (const float*)d_in[3];
    const float* endT      = (const float*)d_in[4];
    const float* trans     = (const float*)d_in[5];
    float* out = (float*)d_out;
    float* ws  = (float*)d_ws;          // BATCH floats of per-batch partials

    fwd_kernel<<<BATCH, 256, 0, stream>>>(emissions, tags, mask, startT, endT, trans, ws);
    reduce_kernel<<<1, 256, 0, stream>>>(ws, out);
}